// Round 2
// baseline (365.741 us; speedup 1.0000x reference)
//
#include <hip/hip_runtime.h>
#include <hip/hip_bf16.h>
#include <cstdint>

// Hierarchical softmax cross-entropy, restructured:
// xent[b] = -(0.1*T1 + 0.9*t2) + 0.1*T3a + 0.9*t3b
//   T1  = sum_{n>=1} prior[n]*s[b,n-1]
//   t2  = sum_{path nodes n>=1} s[b,n-1]
//   T3a = sum_{internal i} lse_i(b) * priorChildSum_i   (priorChildSum_i = sum of prior over i's children)
//   t3b = sum_{internal ancestors of leaf, incl root} lse_i(b)
// lse_i = logsumexp over children of internal node i (contiguous score cols,
// since BFS ids are contiguous). Ancestor matrix input (248 MB) is never read:
// the leaf->root path is recovered from parent pointers derived in hier_setup.

#define LSE_MAX 1024   // num_internal expected ~240; 4x safety margin
                       // (keeps static LDS at ~36.4 KB -> 4 blocks/CU)

__global__ __launch_bounds__(256) void hier_setup(
    const float* __restrict__ prior,
    const int* __restrict__ flat_index,
    const int* __restrict__ child_index,
    const int* __restrict__ p_max_c,
    int E,
    int* __restrict__ parent,
    int* __restrict__ gStart,
    int* __restrict__ gCount,
    float* __restrict__ priorSum)
{
    int j = blockIdx.x * 256 + threadIdx.x;
    if (j >= E) return;
    int mc  = *p_max_c;
    int fi  = flat_index[j];
    int row = fi / mc;
    int col = fi - row * mc;
    int node = child_index[j];        // == j + 1 (BFS), but derive from input
    parent[node] = row;               // parent of every non-root node
    if (col == 0) gStart[row] = j;    // score-column where group i starts
    atomicMax(&gCount[row], col + 1); // group size
    atomicAdd(&priorSum[row], prior[node]);
}

__device__ __forceinline__ float lse_of_group(const float* s_sh, int st, int cnt) {
    float m = -INFINITY, ssum = 0.f;
    for (int t = 0; t < cnt; ++t) {
        float x = s_sh[st + t];
        if (x > m) { ssum = ssum * __expf(m - x) + 1.f; m = x; }
        else       { ssum += __expf(x - m); }
    }
    return m + __logf(ssum);
}

__global__ __launch_bounds__(256) void hier_main(
    const float* __restrict__ scores,
    const int* __restrict__ labels,
    const int* __restrict__ parent,
    const int* __restrict__ gStart,
    const int* __restrict__ gCount,
    const float* __restrict__ priorSum,
    const float* __restrict__ prior,
    const int* __restrict__ p_ni,
    int E,
    float* __restrict__ blockOut)
{
    __shared__ float s_sh[8000];     // scores row (E <= 7999)
    __shared__ float lse_sh[LSE_MAX];
    __shared__ int   path_sh[64];
    __shared__ int   path_len_sh;
    __shared__ float red1[4];
    __shared__ float red2[4];

    const int b   = blockIdx.x;
    const int tid = threadIdx.x;
    const int NI  = *p_ni;

    // Early leaf->root walk on thread 0 (dependent loads overlap the row load).
    if (tid == 0) {
        int cur = NI + labels[b];    // leaf node id
        int d = 0;
        while (cur != 0 && d < 63) { path_sh[d++] = cur; cur = parent[cur]; }
        path_len_sh = d;
    }

    // Stream the scores row into LDS (aligned float4) and fuse T1 = dot(s, prior[1:]).
    const float* rowp = scores + (size_t)b * (size_t)E;
    float t1 = 0.f;
    uintptr_t addr = (uintptr_t)rowp;
    int head = (int)(((16u - (unsigned)(addr & 15u)) & 15u) >> 2);
    if (head > E) head = E;
    for (int c = tid; c < head; c += 256) {
        float v = rowp[c]; s_sh[c] = v; t1 += v * prior[c + 1];
    }
    int nvec = (E - head) >> 2;
    const float4* row4 = (const float4*)(rowp + head);
    for (int v = tid; v < nvec; v += 256) {
        float4 x = row4[v];
        int c = head + v * 4;
        s_sh[c]     = x.x;
        s_sh[c + 1] = x.y;
        s_sh[c + 2] = x.z;
        s_sh[c + 3] = x.w;
        t1 += x.x * prior[c + 1] + x.y * prior[c + 2]
            + x.z * prior[c + 3] + x.w * prior[c + 4];
    }
    for (int c = head + nvec * 4 + tid; c < E; c += 256) {
        float v = rowp[c]; s_sh[c] = v; t1 += v * prior[c + 1];
    }

    __syncthreads();

    // Per-group online log-sum-exp (one group per thread), fuse T3a.
    float t3a = 0.f;
    for (int i = tid; i < NI; i += 256) {
        float l = lse_of_group(s_sh, gStart[i], gCount[i]);
        if (i < LSE_MAX) lse_sh[i] = l;
        t3a += l * priorSum[i];
    }

    __syncthreads();

    // Block-reduce t1, t3a (wave64 shuffle then cross-wave via LDS).
    for (int off = 32; off; off >>= 1) {
        t1  += __shfl_down(t1,  off);
        t3a += __shfl_down(t3a, off);
    }
    int wave = tid >> 6;
    if ((tid & 63) == 0) { red1[wave] = t1; red2[wave] = t3a; }
    __syncthreads();

    if (tid == 0) {
        float T1  = red1[0] + red1[1] + red1[2] + red1[3];
        float T3a = red2[0] + red2[1] + red2[2] + red2[3];
        float t2  = 0.f;
        float t3b = lse_sh[0];           // root (node 0) is always an ancestor
        int d = path_len_sh;
        for (int k = 0; k < d; ++k) {
            int n = path_sh[k];          // path nodes excluding root; k=0 is the leaf
            t2 += s_sh[n - 1];
            if (k >= 1) {                // internal non-root ancestors
                t3b += (n < LSE_MAX) ? lse_sh[n]
                                     : lse_of_group(s_sh, gStart[n], gCount[n]);
            }
        }
        blockOut[b] = -(0.1f * T1 + 0.9f * t2) + 0.1f * T3a + 0.9f * t3b;
    }
}

__global__ __launch_bounds__(256) void hier_reduce(
    const float* __restrict__ blockOut, int B, float* __restrict__ out)
{
    __shared__ double red[4];
    int tid = threadIdx.x;
    double s = 0.0;
    for (int i = tid; i < B; i += 256) s += (double)blockOut[i];
    for (int off = 32; off; off >>= 1) s += __shfl_down(s, off);
    if ((tid & 63) == 0) red[tid >> 6] = s;
    __syncthreads();
    if (tid == 0) out[0] = (float)((red[0] + red[1] + red[2] + red[3]) / (double)B);
}

extern "C" void kernel_launch(void* const* d_in, const int* in_sizes, int n_in,
                              void* d_out, int out_size, void* d_ws, size_t ws_size,
                              hipStream_t stream) {
    const float* scores      = (const float*)d_in[0];
    const int*   labels      = (const int*)  d_in[1];
    // d_in[2] = ancestor matrix: intentionally unused (path from parent pointers)
    const float* prior       = (const float*)d_in[3];
    const int*   flat_index  = (const int*)  d_in[4];
    const int*   child_index = (const int*)  d_in[5];
    const int*   p_ni        = (const int*)  d_in[6];
    const int*   p_mc        = (const int*)  d_in[7];

    const int B = in_sizes[1];   // batch
    const int E = in_sizes[4];   // num_nodes - 1

    // Workspace layout (bytes):
    //   0      parent   [8192 int]   32768
    //   32768  gStart   [4096 int]   16384
    //   49152  gCount   [4096 int]   16384   } zeroed each call
    //   65536  priorSum [4096 float] 16384   }
    //   81920  blockOut [B float]
    char* ws = (char*)d_ws;
    int*   parent   = (int*)  (ws);
    int*   gStart   = (int*)  (ws + 32768);
    int*   gCount   = (int*)  (ws + 49152);
    float* priorSum = (float*)(ws + 65536);
    float* blockOut = (float*)(ws + 81920);

    hipMemsetAsync(ws + 49152, 0, 32768, stream);  // zero gCount + priorSum

    hier_setup<<<(E + 255) / 256, 256, 0, stream>>>(
        prior, flat_index, child_index, p_mc, E, parent, gStart, gCount, priorSum);

    hier_main<<<B, 256, 0, stream>>>(
        scores, labels, parent, gStart, gCount, priorSum, prior, p_ni, E, blockOut);

    hier_reduce<<<1, 256, 0, stream>>>(blockOut, B, (float*)d_out);
}

// Round 3
// 357.136 us; speedup vs baseline: 1.0241x; 1.0241x over previous
//
#include <hip/hip_runtime.h>
#include <hip/hip_bf16.h>
#include <cstdint>

// Hierarchical softmax cross-entropy, restructured (matrix input never read):
// xent[b] = -(0.1*T1 + 0.9*t2) + 0.1*T3a + 0.9*t3b
//   T1  = sum_{n>=1} prior[n]*s[b,n-1]
//   t2  = sum_{path nodes n>=1} s[b,n-1]
//   T3a = sum_{internal i} lse_i(b) * priorChildSum_i
//   t3b = sum_{internal ancestors of leaf, incl root} lse_i(b)
// lse_i = logsumexp over children of internal node i (contiguous score cols,
// BFS ids). Leaf->root path recovered from parent pointers built in hier_setup.

#define LSE_MAX 1024   // num_internal expected ~240; 4x margin

__global__ __launch_bounds__(256) void hier_setup(
    const float* __restrict__ prior,
    const int* __restrict__ flat_index,
    const int* __restrict__ child_index,
    const int* __restrict__ p_max_c,
    int E,
    int* __restrict__ parent,
    int* __restrict__ gStart,
    int* __restrict__ gCount,
    float* __restrict__ priorSum,
    float* __restrict__ P0, float* __restrict__ P1,
    float* __restrict__ P2, float* __restrict__ P3)
{
    int j = blockIdx.x * 256 + threadIdx.x;
    if (j >= E) return;
    int mc  = *p_max_c;
    int fi  = flat_index[j];
    int row = fi / mc;
    int col = fi - row * mc;
    parent[child_index[j]] = row;            // parent of every non-root node

    // Shifted prior copies: P_h[m] = prior[m+h+1] (for aligned float4 dot loads)
    P0[j] = prior[j + 1];
    P1[j] = (j + 2 <= E) ? prior[j + 2] : 0.f;
    P2[j] = (j + 3 <= E) ? prior[j + 3] : 0.f;
    P3[j] = (j + 4 <= E) ? prior[j + 4] : 0.f;

    if (col == 0) {                          // first child scans its own group
        gStart[row] = j;
        int lim = (row + 1) * mc;            // group ends when flat_index leaves row
        float ps = prior[child_index[j]];
        int cnt = 1;
        while (j + cnt < E && flat_index[j + cnt] < lim) {
            ps += prior[child_index[j + cnt]];
            ++cnt;
        }
        gCount[row]   = cnt;                 // plain stores: no memset, no atomics
        priorSum[row] = ps;
    }
}

__device__ __forceinline__ float lse_of_group(const float* S, int st, int cnt) {
    float m = -INFINITY, ssum = 0.f;
    for (int t = 0; t < cnt; ++t) {
        float x = S[st + t];
        if (x > m) { ssum = ssum * __expf(m - x) + 1.f; m = x; }
        else       { ssum += __expf(x - m); }
    }
    return m + __logf(ssum);
}

__global__ __launch_bounds__(256) void hier_main(
    const float* __restrict__ scores,
    const int* __restrict__ labels,
    const int* __restrict__ parent,
    const int* __restrict__ gStart,
    const int* __restrict__ gCount,
    const float* __restrict__ priorSum,
    const float* __restrict__ prior,
    const float* __restrict__ P0, const float* __restrict__ P1,
    const float* __restrict__ P2, const float* __restrict__ P3,
    const int* __restrict__ p_ni,
    int E,
    float* __restrict__ blockOut)
{
    __shared__ __align__(16) float s_sh[8008];  // row, shifted by pad for alignment
    __shared__ float lse_sh[LSE_MAX];
    __shared__ int   path_sh[64];
    __shared__ int   path_len_sh;
    __shared__ float red1[4];
    __shared__ float red2[4];

    const int b   = blockIdx.x;
    const int tid = threadIdx.x;
    const int NI  = *p_ni;

    // Early leaf->root walk on thread 0 (dependent loads overlap the row load).
    if (tid == 0) {
        int cur = NI + labels[b];    // leaf node id
        int d = 0;
        while (cur != 0 && d < 63) { path_sh[d++] = cur; cur = parent[cur]; }
        path_len_sh = d;
    }

    // Row geometry: head = #scalar elems to reach 16B global alignment;
    // pad shifts the row inside LDS so vector stores are 16B-aligned too.
    const float* rowp = scores + (size_t)b * (size_t)E;
    uintptr_t addr = (uintptr_t)rowp;
    int head = (int)(((16u - (unsigned)(addr & 15u)) & 15u) >> 2);   // 0..3
    if (head > E) head = E;
    const int pad = (4 - head) & 3;
    float* S = s_sh + pad;               // S[c] == scores[b][c]
    const float* Ph = (head == 0) ? P0 : (head == 1) ? P1 : (head == 2) ? P2 : P3;

    float t1 = 0.f;
    for (int c = tid; c < head; c += 256) {            // 0..3 scalar head elems
        float v = rowp[c]; S[c] = v; t1 += v * prior[c + 1];
    }
    int nvec = (E - head) >> 2;
    const float4* row4 = (const float4*)(rowp + head);
    for (int v = tid; v < nvec; v += 256) {
        float4 x = row4[v];
        int c = head + v * 4;
        *(float4*)(S + c) = x;                          // aligned ds_write_b128
        float4 p = *(const float4*)(Ph + (c - head));   // aligned, = prior[c+1..c+4]
        t1 += x.x * p.x + x.y * p.y + x.z * p.z + x.w * p.w;
    }
    for (int c = head + nvec * 4 + tid; c < E; c += 256) {   // <=3 tail elems
        float v = rowp[c]; S[c] = v; t1 += v * prior[c + 1];
    }

    __syncthreads();

    // Per-group online log-sum-exp (one group per thread), fuse T3a.
    float t3a = 0.f;
    for (int i = tid; i < NI; i += 256) {
        float l = lse_of_group(S, gStart[i], gCount[i]);
        if (i < LSE_MAX) lse_sh[i] = l;
        t3a += l * priorSum[i];
    }

    __syncthreads();

    // Block-reduce t1, t3a (wave64 shuffle then cross-wave via LDS).
    for (int off = 32; off; off >>= 1) {
        t1  += __shfl_down(t1,  off);
        t3a += __shfl_down(t3a, off);
    }
    int wave = tid >> 6;
    if ((tid & 63) == 0) { red1[wave] = t1; red2[wave] = t3a; }
    __syncthreads();

    if (tid == 0) {
        float T1  = red1[0] + red1[1] + red1[2] + red1[3];
        float T3a = red2[0] + red2[1] + red2[2] + red2[3];
        float t2  = 0.f;
        float t3b = lse_sh[0];           // root (node 0) is always an ancestor
        int d = path_len_sh;
        for (int k = 0; k < d; ++k) {
            int n = path_sh[k];          // path nodes excluding root; k=0 is leaf
            t2 += S[n - 1];
            if (k >= 1) {                // internal non-root ancestors
                t3b += (n < LSE_MAX) ? lse_sh[n]
                                     : lse_of_group(S, gStart[n], gCount[n]);
            }
        }
        blockOut[b] = -(0.1f * T1 + 0.9f * t2) + 0.1f * T3a + 0.9f * t3b;
    }
}

__global__ __launch_bounds__(256) void hier_reduce(
    const float* __restrict__ blockOut, int B, float* __restrict__ out)
{
    __shared__ double red[4];
    int tid = threadIdx.x;
    double s = 0.0;
    for (int i = tid; i < B; i += 256) s += (double)blockOut[i];
    for (int off = 32; off; off >>= 1) s += __shfl_down(s, off);
    if ((tid & 63) == 0) red[tid >> 6] = s;
    __syncthreads();
    if (tid == 0) out[0] = (float)((red[0] + red[1] + red[2] + red[3]) / (double)B);
}

extern "C" void kernel_launch(void* const* d_in, const int* in_sizes, int n_in,
                              void* d_out, int out_size, void* d_ws, size_t ws_size,
                              hipStream_t stream) {
    const float* scores      = (const float*)d_in[0];
    const int*   labels      = (const int*)  d_in[1];
    // d_in[2] = ancestor matrix: intentionally unused (path from parent pointers)
    const float* prior       = (const float*)d_in[3];
    const int*   flat_index  = (const int*)  d_in[4];
    const int*   child_index = (const int*)  d_in[5];
    const int*   p_ni        = (const int*)  d_in[6];
    const int*   p_mc        = (const int*)  d_in[7];

    const int B = in_sizes[1];   // batch
    const int E = in_sizes[4];   // num_nodes - 1

    // Workspace layout (bytes, all 16B-aligned):
    //   0       parent   [8192 int]
    //   32768   gStart   [1024 int]
    //   36864   gCount   [1024 int]
    //   40960   priorSum [1024 float]
    //   49152   P0       [8192 float]   (P_h[m] = prior[m+h+1])
    //   81920   P1       [8192 float]
    //   114688  P2       [8192 float]
    //   147456  P3       [8192 float]
    //   180224  blockOut [B float]
    char* ws = (char*)d_ws;
    int*   parent   = (int*)  (ws);
    int*   gStart   = (int*)  (ws + 32768);
    int*   gCount   = (int*)  (ws + 36864);
    float* priorSum = (float*)(ws + 40960);
    float* P0       = (float*)(ws + 49152);
    float* P1       = (float*)(ws + 81920);
    float* P2       = (float*)(ws + 114688);
    float* P3       = (float*)(ws + 147456);
    float* blockOut = (float*)(ws + 180224);

    hier_setup<<<(E + 255) / 256, 256, 0, stream>>>(
        prior, flat_index, child_index, p_mc, E,
        parent, gStart, gCount, priorSum, P0, P1, P2, P3);

    hier_main<<<B, 256, 0, stream>>>(
        scores, labels, parent, gStart, gCount, priorSum, prior,
        P0, P1, P2, P3, p_ni, E, blockOut);

    hier_reduce<<<1, 256, 0, stream>>>(blockOut, B, (float*)d_out);
}